// Round 2
// baseline (406.006 us; speedup 1.0000x reference)
//
#include <hip/hip_runtime.h>
#include <math.h>

#define P 45
#define N_ITER 20
#define EPW 8   // 4096 blocks, 16 waves/CU resident. Round-1 showed runtime
                // invariant to grid shape -> throughput-bound, not dispatch.
                // This round: kill the LDS pipe (per-CU shared, ~3k cyc/elem)
                // and broadcast c via readlane->SGPR fmac (VALU, per-SIMD).

// Pure-VALU cross-lane add via DPP (no LDS pipe).
template<int CTRL>
__device__ __forceinline__ float dpp_add(float x) {
    int xi = __builtin_bit_cast(int, x);
    int yi = __builtin_amdgcn_update_dpp(0, xi, CTRL, 0xF, 0xF, true);
    return x + __builtin_bit_cast(float, yi);
}

// Full wave64 sum, broadcast to all lanes via readlane -> SGPR.
__device__ __forceinline__ float wave_sum_bcast(float x) {
    x = dpp_add<0x111>(x); // row_shr:1
    x = dpp_add<0x112>(x); // row_shr:2
    x = dpp_add<0x114>(x); // row_shr:4
    x = dpp_add<0x118>(x); // row_shr:8
    x = dpp_add<0x142>(x); // row_bcast:15
    x = dpp_add<0x143>(x); // row_bcast:31 -> lane 63 holds full sum
    int si = __builtin_amdgcn_readlane(__builtin_bit_cast(int, x), 63);
    return __builtin_bit_cast(float, si);
}

// Broadcast lane j's float to all lanes through an SGPR (VALU pipe only).
__device__ __forceinline__ float lane_bcast(float x, int j) {
    int si = __builtin_amdgcn_readlane(__builtin_bit_cast(int, x), j);
    return __builtin_bit_cast(float, si);
}

__device__ __forceinline__ float clamp015(float x) {
    return __builtin_amdgcn_fmed3f(x, 0.0f, 0.15f);
}

__global__ __launch_bounds__(64) void drb_kernel(
    const float* __restrict__ sigma,
    const float* __restrict__ beta,
    const float* __restrict__ w_prev,
    const float* __restrict__ lls,
    const float* __restrict__ llt,
    float* __restrict__ out,
    int B)
{
    const int lane  = threadIdx.x;
    const bool active = lane < P;
    const bool ones   = (lane == P);
    const int  cidx   = active ? lane : 0;

    const float lam_s  = expf(lls[0]);
    const float lam_t2 = 2.0f * expf(llt[0]);

    const int b0   = blockIdx.x * EPW;
    const int bend = min(b0 + EPW, B);

    for (int b = b0; b < bend; ++b) {
        // Loop-invariant gradient part: -beta - 2*lam_t*w_prev.
        float base = 0.0f;
        if (active) {
            base = -beta[(size_t)b * P + lane]
                 - lam_t2 * w_prev[(size_t)b * P + lane];
        }

        // sigma is bitwise symmetric: row i == column i -> coalesced column
        // loads (lane-contiguous, 45 loads with immediate offsets off one
        // address pair; max offset 44*180=7920 < 8192 signed-13b imm).
        // Lanes > P: zero rows -> all downstream stays exactly 0.
        // Lane P (45): all-ONES row -> its matvec output = sum(c), which
        // replaces a 7-instr DPP reduction with one readlane.
        const float* sp = sigma + (size_t)b * (P * P) + cidx;
        float row[P];
        #pragma unroll
        for (int j = 0; j < P; ++j) {
            float v = sp[(size_t)j * P];
            row[j] = ones ? 1.0f : (active ? v : 0.0f);
        }

        // State: c = pre-scale weights; true w = c * r, r = rcp(sum(c)+eps)
        // obtained for free from the ones-row matvec output.
        float c = active ? (float)(1.0 / 45.0) : 0.0f;

        for (int it = 0; it < N_ITER; ++it) {
            // acc_i = row_i . c. c_j broadcast lane->SGPR via readlane;
            // v_fmac_f32 with one SGPR operand is legal and full-rate.
            // 4 accumulator chains keep dep depth ~12.
            float a0 = 0.0f, a1 = 0.0f, a2 = 0.0f, a3 = 0.0f;
            #pragma unroll
            for (int j = 0; j < P - 1; j += 4) {
                const float c0 = lane_bcast(c, j);
                const float c1 = lane_bcast(c, j + 1);
                const float c2 = lane_bcast(c, j + 2);
                const float c3 = lane_bcast(c, j + 3);
                a0 = fmaf(c0, row[j],     a0);
                a1 = fmaf(c1, row[j + 1], a1);
                a2 = fmaf(c2, row[j + 2], a2);
                a3 = fmaf(c3, row[j + 3], a3);
            }
            a0 = fmaf(lane_bcast(c, P - 1), row[P - 1], a0);
            const float acc = (a0 + a2) + (a1 + a3);

            // sum(c) falls out of lane 45's ones-row dot product.
            const float s2 = lane_bcast(acc, P);
            const float r = __builtin_amdgcn_rcpf(s2 + 1e-8f);

            // w_i = c_i * r;  Sw_i = r * acc
            const float t = c * r;
            float g = fmaf(lam_t2, t, base);
            g += (c > 0.0f) ? lam_s : 0.0f;
            g = fmaf(r + r, acc, g);
            const float x = fmaf(-0.05f, g, t);

            // projection: clip, renorm, clip; final renorm deferred.
            const float a  = clamp015(x);
            const float s1 = wave_sum_bcast(a);
            const float r1 = __builtin_amdgcn_rcpf(s1 + 1e-8f);
            c = clamp015(a * r1);
            // lane 45: acc = sum(c) -> x < 0 -> a = 0 -> stays exactly 0.
            // Lanes 46-63: everything 0 -> stay 0.
        }

        // Epilogue: apply the final deferred normalize.
        const float sf = wave_sum_bcast(c);
        const float rf = __builtin_amdgcn_rcpf(sf + 1e-8f);
        if (active) out[(size_t)b * P + lane] = c * rf;
    }
}

extern "C" void kernel_launch(void* const* d_in, const int* in_sizes, int n_in,
                              void* d_out, int out_size, void* d_ws, size_t ws_size,
                              hipStream_t stream) {
    const float* sigma  = (const float*)d_in[0];
    const float* beta   = (const float*)d_in[1];
    const float* w_prev = (const float*)d_in[2];
    const float* lls    = (const float*)d_in[3];
    const float* llt    = (const float*)d_in[4];
    float* out = (float*)d_out;

    const int B = in_sizes[1] / P;   // 32768
    const int grid = (B + EPW - 1) / EPW;
    drb_kernel<<<grid, 64, 0, stream>>>(sigma, beta, w_prev, lls, llt, out, B);
}

// Round 3
// 376.474 us; speedup vs baseline: 1.0784x; 1.0784x over previous
//
#include <hip/hip_runtime.h>
#include <math.h>

#define P 45
#define N_ITER 20

typedef float v2f __attribute__((ext_vector_type(2)));
typedef float v4f __attribute__((ext_vector_type(4)));

// Pure-VALU cross-lane add via DPP (no LDS pipe).
template<int CTRL>
__device__ __forceinline__ float dpp_add(float x) {
    int xi = __builtin_bit_cast(int, x);
    int yi = __builtin_amdgcn_update_dpp(0, xi, CTRL, 0xF, 0xF, true);
    return x + __builtin_bit_cast(float, yi);
}

// Full wave64 sum, broadcast to all lanes via readlane -> SGPR.
__device__ __forceinline__ float wave_sum_bcast(float x) {
    x = dpp_add<0x111>(x); // row_shr:1
    x = dpp_add<0x112>(x); // row_shr:2
    x = dpp_add<0x114>(x); // row_shr:4
    x = dpp_add<0x118>(x); // row_shr:8
    x = dpp_add<0x142>(x); // row_bcast:15
    x = dpp_add<0x143>(x); // row_bcast:31 -> lane 63 holds full sum
    int si = __builtin_amdgcn_readlane(__builtin_bit_cast(int, x), 63);
    return __builtin_bit_cast(float, si);
}

__device__ __forceinline__ float clamp015(float x) {
    return __builtin_amdgcn_fmed3f(x, 0.0f, 0.15f);
}

// Round-3 note: R1 (EPW=8) and R2 (LDS->readlane) both regressed dur_us by
// +14/+30 us on what is now understood to be a ~320 us re-poison pedestal
// (two 1.06 GB fillBuffer dispatches @ ~160 us inside the timed window;
// drb_kernel itself is <156 us in every round's top-5). This reverts to the
// round-0 structure (best kernel component, ~56 us vs a 44 us HBM floor),
// keeping only the free 4-way accumulator split from R2.
__global__ __launch_bounds__(64) void drb_kernel(
    const float* __restrict__ sigma,
    const float* __restrict__ beta,
    const float* __restrict__ w_prev,
    const float* __restrict__ lls,
    const float* __restrict__ llt,
    float* __restrict__ out)
{
    const int b    = blockIdx.x;
    const int lane = threadIdx.x;
    const bool active = lane < P;

    const float lam_s  = expf(lls[0]);
    const float lam_t2 = 2.0f * expf(llt[0]);

    // Loop-invariant gradient part: -beta - 2*lam_t*w_prev.
    float base = 0.0f;
    if (active) {
        base = -beta[(size_t)b * P + lane]
               - lam_t2 * w_prev[(size_t)b * P + lane];
    }

    // sigma is bitwise symmetric: row i == column i -> coalesced column loads.
    // Lanes > P: zero rows (exact-zero contributions, no per-iter masking).
    // Lane P (45) gets an all-ONES row: its matvec output = sum(c), which
    // replaces a whole 7-instr DPP reduction with one readlane.
    const int cidx = active ? lane : 0;
    const float* sp = sigma + (size_t)b * (P * P) + cidx;
    float rv[P + 1];
    #pragma unroll
    for (int j = 0; j < P; ++j) {
        float v = sp[(size_t)j * P];
        rv[j] = active ? v : 0.0f;
    }
    rv[P] = 0.0f;
    const bool ones = (lane == P);
    v2f row2[23];
    #pragma unroll
    for (int k = 0; k < 23; ++k) {
        float lo = ones ? 1.0f : rv[2 * k];
        float hi = (2 * k + 1 < P) ? (ones ? 1.0f : rv[2 * k + 1]) : 0.0f;
        v2f t; t.x = lo; t.y = hi;
        row2[k] = t;
    }
    #pragma unroll
    for (int k = 0; k < 23; ++k) asm volatile("" : "+v"(row2[k]));  // pin

    // Double-buffered 64-float w slots (kills write-after-read across iters).
    __shared__ __align__(16) float sh[128];

    // State: c = pre-scale weights; true w = c * r, r = rcp(sum(c)+eps)
    // obtained for free from the ones-row matvec output.
    float c = active ? (float)(1.0 / 45.0) : 0.0f;

    for (int it = 0; it < N_ITER; ++it) {
        float* shb = sh + ((it & 1) << 6);
        shb[lane] = c;               // lanes >= P publish exact zeros
        __syncthreads();             // 1 wave: cheap; orders write -> reads
        const v4f* shv = (const v4f*)shb;

        // acc_i = row_i . c via packed-fp32 FMAs; broadcast w read as b128.
        // 4 accumulator chains: dep depth ~6 instead of ~11.
        v2f accA; accA.x = 0.0f; accA.y = 0.0f;
        v2f accB = accA, accC = accA, accD = accA;
        #pragma unroll
        for (int k = 0; k < 11; ++k) {
            v4f q = shv[k];
            v2f lo; lo.x = q.x; lo.y = q.y;
            v2f hi; hi.x = q.z; hi.y = q.w;
            if (k & 1) {
                accC = __builtin_elementwise_fma(row2[2 * k],     lo, accC);
                accD = __builtin_elementwise_fma(row2[2 * k + 1], hi, accD);
            } else {
                accA = __builtin_elementwise_fma(row2[2 * k],     lo, accA);
                accB = __builtin_elementwise_fma(row2[2 * k + 1], hi, accB);
            }
        }
        {
            v4f q = shv[11];
            v2f lo; lo.x = q.x; lo.y = q.y;   // floats 44,45 (45 is zero slot)
            accC = __builtin_elementwise_fma(row2[22], lo, accC);
        }
        v2f am = (accA + accC) + (accB + accD);
        const float acc = am.x + am.y;

        // sum(c) falls out of lane 45's ones-row dot product.
        const float s2 = __builtin_bit_cast(float,
            __builtin_amdgcn_readlane(__builtin_bit_cast(int, acc), P));
        const float r = __builtin_amdgcn_rcpf(s2 + 1e-8f);

        // w_i = c_i * r;  Sw_i = r * acc
        const float t = c * r;
        float g = fmaf(lam_t2, t, base);
        g += (c > 0.0f) ? lam_s : 0.0f;
        g = fmaf(r + r, acc, g);
        const float x = fmaf(-0.05f, g, t);

        // projection: clip, renorm, clip; final renorm deferred.
        const float a  = clamp015(x);
        const float s1 = wave_sum_bcast(a);
        const float r1 = __builtin_amdgcn_rcpf(s1 + 1e-8f);
        c = clamp015(a * r1);
        // lane 45: acc = sum(c) -> x < 0 -> a = 0 -> stays exactly 0. Lanes
        // 46-63: everything 0 -> stay 0. So slots 45..47 read above are 0.
    }

    // Epilogue: apply the final deferred normalize.
    const float sf = wave_sum_bcast(c);
    const float rf = __builtin_amdgcn_rcpf(sf + 1e-8f);
    if (active) out[(size_t)b * P + lane] = c * rf;
}

extern "C" void kernel_launch(void* const* d_in, const int* in_sizes, int n_in,
                              void* d_out, int out_size, void* d_ws, size_t ws_size,
                              hipStream_t stream) {
    const float* sigma  = (const float*)d_in[0];
    const float* beta   = (const float*)d_in[1];
    const float* w_prev = (const float*)d_in[2];
    const float* lls    = (const float*)d_in[3];
    const float* llt    = (const float*)d_in[4];
    float* out = (float*)d_out;

    const int B = in_sizes[1] / P;   // 32768
    drb_kernel<<<B, 64, 0, stream>>>(sigma, beta, w_prev, lls, llt, out);
}